// Round 3
// baseline (916.676 us; speedup 1.0000x reference)
//
#include <hip/hip_runtime.h>
#include <hip/hip_bf16.h>

#define PDIM 4096
#define PPN ((size_t)PDIM * (size_t)PDIM)

typedef __attribute__((ext_vector_type(8))) short bf16x8;
typedef __attribute__((ext_vector_type(4))) float floatx4;

__device__ __forceinline__ void load_lds16(const __hip_bfloat16* g, void* l) {
  __builtin_amdgcn_global_load_lds(
      (const __attribute__((address_space(1))) void*)g,
      (__attribute__((address_space(3))) void*)l, 16, 0, 0);
}

__device__ __forceinline__ unsigned short bf16bits(float f) {
  __hip_bfloat16 h = __float2bfloat16(f);
  return *(unsigned short*)&h;
}

// ---- ||X||_F^2: grid-stride, 1 atomic per block ----
__global__ void sumsq(const float4* __restrict__ x, float* __restrict__ acc) {
  float s = 0.f;
  const size_t n4 = PPN / 4;
  for (size_t i = (size_t)blockIdx.x * 256 + threadIdx.x; i < n4;
       i += (size_t)gridDim.x * 256) {
    const float4 v = x[i];
    s += v.x * v.x + v.y * v.y + v.z * v.z + v.w * v.w;
  }
#pragma unroll
  for (int off = 32; off > 0; off >>= 1) s += __shfl_down(s, off);
  __shared__ float ws[4];
  if ((threadIdx.x & 63) == 0) ws[threadIdx.x >> 6] = s;
  __syncthreads();
  if (threadIdx.x == 0) atomicAdd(acc, ws[0] + ws[1] + ws[2] + ws[3]);
}

// ---- fp32 -> bf16 cast + bf16 transpose ----
__global__ void cast_nt(const float* __restrict__ src,
                        __hip_bfloat16* __restrict__ dstN,
                        __hip_bfloat16* __restrict__ dstT) {
  __shared__ float tile[64][65];
  const int bx = blockIdx.x * 64, by = blockIdx.y * 64;
  const int tx = threadIdx.x & 15, ty = threadIdx.x >> 4;
#pragma unroll
  for (int r = 0; r < 4; ++r) {
    const int row = ty + r * 16;
    const float4 v = *(const float4*)&src[(size_t)(by + row) * PDIM + bx + tx * 4];
    tile[row][tx * 4 + 0] = v.x;
    tile[row][tx * 4 + 1] = v.y;
    tile[row][tx * 4 + 2] = v.z;
    tile[row][tx * 4 + 3] = v.w;
    ushort4 o;
    o.x = bf16bits(v.x); o.y = bf16bits(v.y); o.z = bf16bits(v.z); o.w = bf16bits(v.w);
    *(ushort4*)&dstN[(size_t)(by + row) * PDIM + bx + tx * 4] = o;
  }
  __syncthreads();
#pragma unroll
  for (int r = 0; r < 4; ++r) {
    const int i = ty + r * 16;
    ushort4 o;
    o.x = bf16bits(tile[tx * 4 + 0][i]);
    o.y = bf16bits(tile[tx * 4 + 1][i]);
    o.z = bf16bits(tile[tx * 4 + 2][i]);
    o.w = bf16bits(tile[tx * 4 + 3][i]);
    *(ushort4*)&dstT[(size_t)(bx + i) * PDIM + by + tx * 4] = o;
  }
}

// ---- W_beta: cast + row-sum + scale[i] = W^2/(s*W^2+1) ----
__global__ void cast_wb_rows(const float* __restrict__ Wb,
                             __hip_bfloat16* __restrict__ Wbb,
                             const float* __restrict__ sAcc,
                             float* __restrict__ scale) {
  const size_t row = blockIdx.x;
  const float4* src = (const float4*)(Wb + row * PDIM);
  ushort4* dst = (ushort4*)(Wbb + row * PDIM);
  float sum = 0.f;
#pragma unroll
  for (int it = 0; it < 4; ++it) {
    const int j = threadIdx.x + it * 256;
    const float4 v = src[j];
    sum += (v.x + v.y) + (v.z + v.w);
    ushort4 o;
    o.x = bf16bits(v.x); o.y = bf16bits(v.y); o.z = bf16bits(v.z); o.w = bf16bits(v.w);
    dst[j] = o;
  }
#pragma unroll
  for (int off = 32; off > 0; off >>= 1) sum += __shfl_down(sum, off);
  __shared__ float ws[4];
  if ((threadIdx.x & 63) == 0) ws[threadIdx.x >> 6] = sum;
  __syncthreads();
  if (threadIdx.x == 0) {
    const float W = ws[0] + ws[1] + ws[2] + ws[3];
    const float w2 = W * W;
    scale[row] = w2 / ((*sAcc) * w2 + 1.0f);
  }
}

// ---- NT GEMM, 128x128 tile, BK=32, double-buffered LDS, 1 barrier/iter ----
// Serpentine 16x16-supertile swizzle for L2/L3 locality (1D grid of 1024).
template <int MODE>
__global__ __launch_bounds__(256)
void gemm_nt(const __hip_bfloat16* __restrict__ A,
             const __hip_bfloat16* __restrict__ B,
             const float* __restrict__ scale,
             float* __restrict__ outF,
             __hip_bfloat16* __restrict__ outB,
             const __hip_bfloat16* __restrict__ sub,
             float* __restrict__ lossAcc) {
  __shared__ __align__(16) __hip_bfloat16 As[2][128 * 32];
  __shared__ __align__(16) __hip_bfloat16 Bs[2][128 * 32];

  const int tid = threadIdx.x;
  const int lane = tid & 63;
  const int wave = tid >> 6;
  const int wm = wave >> 1, wn = wave & 1;

  // serpentine supertile swizzle: 32x32 block grid as 2x2 supertiles of 16x16
  const int bid = blockIdx.x;
  const int st = bid >> 8;               // 0..3
  const int idx = bid & 255;
  const int sr = st >> 1;
  const int scc = (st & 1) ^ (sr & 1);   // serpentine over supertile cols
  const int by = sr * 16 + (idx >> 4);
  const int bx = scc * 16 + (idx & 15);

  const size_t rowA0 = (size_t)by * 128;
  const size_t rowB0 = (size_t)bx * 128;

  const int c0 = tid, c1 = tid + 256;
  const __hip_bfloat16* gA0 = A + (rowA0 + (size_t)(c0 >> 2)) * PDIM + (c0 & 3) * 8;
  const __hip_bfloat16* gA1 = A + (rowA0 + (size_t)(c1 >> 2)) * PDIM + (c1 & 3) * 8;
  const __hip_bfloat16* gB0 = B + (rowB0 + (size_t)(c0 >> 2)) * PDIM + (c0 & 3) * 8;
  const __hip_bfloat16* gB1 = B + (rowB0 + (size_t)(c1 >> 2)) * PDIM + (c1 & 3) * 8;

  floatx4 acc[4][4] = {};

  const int fr = lane & 15;
  const int fq = (lane >> 4) * 8;

  // preload tile 0 into buffer 0
  {
    char* a0 = (char*)As[0] + wave * 1024;
    char* b0 = (char*)Bs[0] + wave * 1024;
    load_lds16(gA0, a0);
    load_lds16(gA1, a0 + 4096);
    load_lds16(gB0, b0);
    load_lds16(gB1, b0 + 4096);
  }
  __syncthreads();

  int p = 0;
  for (int kt = 32; kt < PDIM; kt += 32) {
    // issue next tile's loads into buffer p^1 (no wait)
    {
      char* a0 = (char*)As[p ^ 1] + wave * 1024;
      char* b0 = (char*)Bs[p ^ 1] + wave * 1024;
      load_lds16(gA0 + kt, a0);
      load_lds16(gA1 + kt, a0 + 4096);
      load_lds16(gB0 + kt, b0);
      load_lds16(gB1 + kt, b0 + 4096);
    }
    // compute on buffer p
    const __hip_bfloat16* Ab = As[p];
    const __hip_bfloat16* Bb = Bs[p];
    bf16x8 af[4], bfr[4];
#pragma unroll
    for (int mi = 0; mi < 4; ++mi)
      af[mi] = *(const bf16x8*)&Ab[(wm * 64 + mi * 16 + fr) * 32 + fq];
#pragma unroll
    for (int ni = 0; ni < 4; ++ni)
      bfr[ni] = *(const bf16x8*)&Bb[(wn * 64 + ni * 16 + fr) * 32 + fq];
#pragma unroll
    for (int mi = 0; mi < 4; ++mi)
#pragma unroll
      for (int ni = 0; ni < 4; ++ni)
        acc[mi][ni] = __builtin_amdgcn_mfma_f32_16x16x32_bf16(
            af[mi], bfr[ni], acc[mi][ni], 0, 0, 0);
    __syncthreads();  // drains next tile's loads (in flight during MFMA)
    p ^= 1;
  }
  // last tile
  {
    const __hip_bfloat16* Ab = As[p];
    const __hip_bfloat16* Bb = Bs[p];
    bf16x8 af[4], bfr[4];
#pragma unroll
    for (int mi = 0; mi < 4; ++mi)
      af[mi] = *(const bf16x8*)&Ab[(wm * 64 + mi * 16 + fr) * 32 + fq];
#pragma unroll
    for (int ni = 0; ni < 4; ++ni)
      bfr[ni] = *(const bf16x8*)&Bb[(wn * 64 + ni * 16 + fr) * 32 + fq];
#pragma unroll
    for (int mi = 0; mi < 4; ++mi)
#pragma unroll
      for (int ni = 0; ni < 4; ++ni)
        acc[mi][ni] = __builtin_amdgcn_mfma_f32_16x16x32_bf16(
            af[mi], bfr[ni], acc[mi][ni], 0, 0, 0);
  }

  const size_t row0 = rowA0 + wm * 64;
  const size_t col0 = rowB0 + wn * 64;
  const int lr = (lane >> 4) << 2;
  const int lc = lane & 15;

  if constexpr (MODE == 2) {
    float tot = 0.f;
#pragma unroll
    for (int mi = 0; mi < 4; ++mi)
#pragma unroll
      for (int ni = 0; ni < 4; ++ni)
#pragma unroll
        for (int r = 0; r < 4; ++r) tot += acc[mi][ni][r] * acc[mi][ni][r];
#pragma unroll
    for (int off = 32; off > 0; off >>= 1) tot += __shfl_down(tot, off);
    __shared__ float ws[4];
    if (lane == 0) ws[wave] = tot;
    __syncthreads();
    if (tid == 0) atomicAdd(lossAcc, ws[0] + ws[1] + ws[2] + ws[3]);
  } else if constexpr (MODE == 0) {
#pragma unroll
    for (int mi = 0; mi < 4; ++mi) {
#pragma unroll
      for (int r = 0; r < 4; ++r) {
        const size_t row = row0 + mi * 16 + lr + r;
        const float sc = scale[row];
#pragma unroll
        for (int ni = 0; ni < 4; ++ni) {
          const size_t col = col0 + ni * 16 + lc;
          const float v = sc * acc[mi][ni][r];
          outF[row * PDIM + col] = v;
          outB[row * PDIM + col] = __float2bfloat16(v);
        }
      }
    }
  } else {
#pragma unroll
    for (int mi = 0; mi < 4; ++mi) {
#pragma unroll
      for (int r = 0; r < 4; ++r) {
        const size_t row = row0 + mi * 16 + lr + r;
#pragma unroll
        for (int ni = 0; ni < 4; ++ni) {
          const size_t col = col0 + ni * 16 + lc;
          const float v = acc[mi][ni][r] - __bfloat162float(sub[row * PDIM + col]);
          outB[row * PDIM + col] = __float2bfloat16(v);
        }
      }
    }
  }
}

__global__ void finalize(float* __restrict__ out, const float* __restrict__ acc) {
  if (threadIdx.x == 0) out[0] = sqrtf(*acc);
}

extern "C" void kernel_launch(void* const* d_in, const int* in_sizes, int n_in,
                              void* d_out, int out_size, void* d_ws, size_t ws_size,
                              hipStream_t stream) {
  const float* X  = (const float*)d_in[0];
  const float* Y  = (const float*)d_in[1];
  const float* Wb = (const float*)d_in[2];
  float* out = (float*)d_out;  // [0]=loss, [1..]=W_matrix (fp32)

  __hip_bfloat16* Xb  = (__hip_bfloat16*)d_ws;
  __hip_bfloat16* XbT = Xb + PPN;
  __hip_bfloat16* Yb  = XbT + PPN;
  __hip_bfloat16* YbT = Yb + PPN;
  __hip_bfloat16* Wbb = YbT + PPN;
  __hip_bfloat16* Wmb = Wbb + PPN;
  __hip_bfloat16* PTb = Xb;  // aliases Xb (dead after GEMM1)
  float* scale   = (float*)(Wmb + PPN);
  float* sAcc    = scale + PDIM;
  float* lossAcc = sAcc + 1;

  hipMemsetAsync(sAcc, 0, 2 * sizeof(float), stream);

  sumsq<<<1024, 256, 0, stream>>>((const float4*)X, sAcc);

  dim3 cgrid(PDIM / 64, PDIM / 64);
  cast_nt<<<cgrid, 256, 0, stream>>>(X, Xb, XbT);
  cast_nt<<<cgrid, 256, 0, stream>>>(Y, Yb, YbT);
  cast_wb_rows<<<PDIM, 256, 0, stream>>>(Wb, Wbb, sAcc, scale);

  const int ggrid = (PDIM / 128) * (PDIM / 128);  // 1024, swizzled in-kernel
  gemm_nt<0><<<ggrid, 256, 0, stream>>>(Yb, Xb, scale, out + 1, Wmb, nullptr, nullptr);
  gemm_nt<1><<<ggrid, 256, 0, stream>>>(XbT, Wmb, nullptr, nullptr, PTb, YbT, nullptr);
  gemm_nt<2><<<ggrid, 256, 0, stream>>>(PTb, Wbb, nullptr, nullptr, nullptr, nullptr, lossAcc);

  finalize<<<1, 1, 0, stream>>>(out, lossAcc);
}

// Round 4
// 815.253 us; speedup vs baseline: 1.1244x; 1.1244x over previous
//
#include <hip/hip_runtime.h>
#include <hip/hip_bf16.h>

#define PDIM 4096
#define PPN ((size_t)PDIM * (size_t)PDIM)

typedef __attribute__((ext_vector_type(8))) short bf16x8;
typedef __attribute__((ext_vector_type(4))) float floatx4;

__device__ __forceinline__ void load_lds16(const __hip_bfloat16* g, void* l) {
  __builtin_amdgcn_global_load_lds(
      (const __attribute__((address_space(1))) void*)g,
      (__attribute__((address_space(3))) void*)l, 16, 0, 0);
}

__device__ __forceinline__ unsigned short bf16bits(float f) {
  __hip_bfloat16 h = __float2bfloat16(f);
  return *(unsigned short*)&h;
}

// ---- ||X||_F^2: grid-stride, 1 atomic per block ----
__global__ void sumsq(const float4* __restrict__ x, float* __restrict__ acc) {
  float s = 0.f;
  const size_t n4 = PPN / 4;
  for (size_t i = (size_t)blockIdx.x * 256 + threadIdx.x; i < n4;
       i += (size_t)gridDim.x * 256) {
    const float4 v = x[i];
    s += v.x * v.x + v.y * v.y + v.z * v.z + v.w * v.w;
  }
#pragma unroll
  for (int off = 32; off > 0; off >>= 1) s += __shfl_down(s, off);
  __shared__ float ws[4];
  if ((threadIdx.x & 63) == 0) ws[threadIdx.x >> 6] = s;
  __syncthreads();
  if (threadIdx.x == 0) atomicAdd(acc, ws[0] + ws[1] + ws[2] + ws[3]);
}

// ---- fp32 -> bf16 cast + bf16 transpose ----
__global__ void cast_nt(const float* __restrict__ src,
                        __hip_bfloat16* __restrict__ dstN,
                        __hip_bfloat16* __restrict__ dstT) {
  __shared__ float tile[64][65];
  const int bx = blockIdx.x * 64, by = blockIdx.y * 64;
  const int tx = threadIdx.x & 15, ty = threadIdx.x >> 4;
#pragma unroll
  for (int r = 0; r < 4; ++r) {
    const int row = ty + r * 16;
    const float4 v = *(const float4*)&src[(size_t)(by + row) * PDIM + bx + tx * 4];
    tile[row][tx * 4 + 0] = v.x;
    tile[row][tx * 4 + 1] = v.y;
    tile[row][tx * 4 + 2] = v.z;
    tile[row][tx * 4 + 3] = v.w;
    ushort4 o;
    o.x = bf16bits(v.x); o.y = bf16bits(v.y); o.z = bf16bits(v.z); o.w = bf16bits(v.w);
    *(ushort4*)&dstN[(size_t)(by + row) * PDIM + bx + tx * 4] = o;
  }
  __syncthreads();
#pragma unroll
  for (int r = 0; r < 4; ++r) {
    const int i = ty + r * 16;
    ushort4 o;
    o.x = bf16bits(tile[tx * 4 + 0][i]);
    o.y = bf16bits(tile[tx * 4 + 1][i]);
    o.z = bf16bits(tile[tx * 4 + 2][i]);
    o.w = bf16bits(tile[tx * 4 + 3][i]);
    *(ushort4*)&dstT[(size_t)(bx + i) * PDIM + by + tx * 4] = o;
  }
}

// ---- W_beta: cast + row-sum + scale[i] = W^2/(s*W^2+1) ----
__global__ void cast_wb_rows(const float* __restrict__ Wb,
                             __hip_bfloat16* __restrict__ Wbb,
                             const float* __restrict__ sAcc,
                             float* __restrict__ scale) {
  const size_t row = blockIdx.x;
  const float4* src = (const float4*)(Wb + row * PDIM);
  ushort4* dst = (ushort4*)(Wbb + row * PDIM);
  float sum = 0.f;
#pragma unroll
  for (int it = 0; it < 4; ++it) {
    const int j = threadIdx.x + it * 256;
    const float4 v = src[j];
    sum += (v.x + v.y) + (v.z + v.w);
    ushort4 o;
    o.x = bf16bits(v.x); o.y = bf16bits(v.y); o.z = bf16bits(v.z); o.w = bf16bits(v.w);
    dst[j] = o;
  }
#pragma unroll
  for (int off = 32; off > 0; off >>= 1) sum += __shfl_down(sum, off);
  __shared__ float ws[4];
  if ((threadIdx.x & 63) == 0) ws[threadIdx.x >> 6] = sum;
  __syncthreads();
  if (threadIdx.x == 0) {
    const float W = ws[0] + ws[1] + ws[2] + ws[3];
    const float w2 = W * W;
    scale[row] = w2 / ((*sAcc) * w2 + 1.0f);
  }
}

// ---- NT GEMM: C[i,j] = sum_k A[i,k]*B[j,k], 128x128 tile, BK=32 ----
// XOR chunk swizzle: LDS slot (r,c') holds global chunk (r, c'^((r>>1)&3)).
// Kills the 8-way ds_read_b128 bank conflict (write side stays contiguous
// for global_load_lds; read offset uses the same XOR).
template <int MODE>
__global__ __launch_bounds__(256)
void gemm_nt(const __hip_bfloat16* __restrict__ A,
             const __hip_bfloat16* __restrict__ B,
             const float* __restrict__ scale,
             float* __restrict__ outF,
             __hip_bfloat16* __restrict__ outB,
             const __hip_bfloat16* __restrict__ sub,
             float* __restrict__ lossAcc) {
  __shared__ __align__(16) __hip_bfloat16 As[128 * 32];
  __shared__ __align__(16) __hip_bfloat16 Bs[128 * 32];

  const int tid = threadIdx.x;
  const int lane = tid & 63;
  const int wave = tid >> 6;
  const int wm = wave >> 1, wn = wave & 1;

  const size_t rowA0 = (size_t)blockIdx.y * 128;
  const size_t rowB0 = (size_t)blockIdx.x * 128;

  // staging: chunk c -> (row r=c>>2, lds col c&3); fetch global col chunk
  // (c&3) ^ ((r>>1)&3) so frag reads are conflict-free.
  const int c0 = tid, c1 = tid + 256;
  const int r0 = c0 >> 2, r1 = c1 >> 2;
  const int sc0 = (c0 & 3) ^ ((r0 >> 1) & 3);
  const int sc1 = (c1 & 3) ^ ((r1 >> 1) & 3);
  const __hip_bfloat16* gA0 = A + (rowA0 + (size_t)r0) * PDIM + sc0 * 8;
  const __hip_bfloat16* gA1 = A + (rowA0 + (size_t)r1) * PDIM + sc1 * 8;
  const __hip_bfloat16* gB0 = B + (rowB0 + (size_t)r0) * PDIM + sc0 * 8;
  const __hip_bfloat16* gB1 = B + (rowB0 + (size_t)r1) * PDIM + sc1 * 8;

  char* ldsA0 = (char*)As + wave * 1024;
  char* ldsA1 = (char*)As + 4096 + wave * 1024;
  char* ldsB0 = (char*)Bs + wave * 1024;
  char* ldsB1 = (char*)Bs + 4096 + wave * 1024;

  floatx4 acc[4][4] = {};

  const int fr = lane & 15;              // row-in-16
  const int kq = lane >> 4;              // k-chunk 0..3
  const int sw = (fr >> 1) & 3;          // swizzle select (mi-invariant)
  const int ko = (kq ^ sw) * 16;         // byte offset of chunk within row

  for (int kt = 0; kt < PDIM; kt += 32) {
    load_lds16(gA0 + kt, ldsA0);
    load_lds16(gA1 + kt, ldsA1);
    load_lds16(gB0 + kt, ldsB0);
    load_lds16(gB1 + kt, ldsB1);
    __syncthreads();

    bf16x8 af[4], bfr[4];
#pragma unroll
    for (int mi = 0; mi < 4; ++mi)
      af[mi] = *(const bf16x8*)((const char*)As + (wm * 64 + mi * 16 + fr) * 64 + ko);
#pragma unroll
    for (int ni = 0; ni < 4; ++ni)
      bfr[ni] = *(const bf16x8*)((const char*)Bs + (wn * 64 + ni * 16 + fr) * 64 + ko);
#pragma unroll
    for (int mi = 0; mi < 4; ++mi)
#pragma unroll
      for (int ni = 0; ni < 4; ++ni)
        acc[mi][ni] = __builtin_amdgcn_mfma_f32_16x16x32_bf16(
            af[mi], bfr[ni], acc[mi][ni], 0, 0, 0);
    __syncthreads();
  }

  const size_t row0 = rowA0 + wm * 64;
  const size_t col0 = rowB0 + wn * 64;
  const int lr = (lane >> 4) << 2;
  const int lc = lane & 15;

  if constexpr (MODE == 2) {
    float tot = 0.f;
#pragma unroll
    for (int mi = 0; mi < 4; ++mi)
#pragma unroll
      for (int ni = 0; ni < 4; ++ni)
#pragma unroll
        for (int r = 0; r < 4; ++r) tot += acc[mi][ni][r] * acc[mi][ni][r];
#pragma unroll
    for (int off = 32; off > 0; off >>= 1) tot += __shfl_down(tot, off);
    __shared__ float ws[4];
    if (lane == 0) ws[wave] = tot;
    __syncthreads();
    if (tid == 0) atomicAdd(lossAcc, ws[0] + ws[1] + ws[2] + ws[3]);
  } else if constexpr (MODE == 0) {
#pragma unroll
    for (int mi = 0; mi < 4; ++mi) {
#pragma unroll
      for (int r = 0; r < 4; ++r) {
        const size_t row = row0 + mi * 16 + lr + r;
        const float sc = scale[row];
#pragma unroll
        for (int ni = 0; ni < 4; ++ni) {
          const size_t col = col0 + ni * 16 + lc;
          const float v = sc * acc[mi][ni][r];
          outF[row * PDIM + col] = v;
          outB[row * PDIM + col] = __float2bfloat16(v);
        }
      }
    }
  } else {
#pragma unroll
    for (int mi = 0; mi < 4; ++mi) {
#pragma unroll
      for (int r = 0; r < 4; ++r) {
        const size_t row = row0 + mi * 16 + lr + r;
#pragma unroll
        for (int ni = 0; ni < 4; ++ni) {
          const size_t col = col0 + ni * 16 + lc;
          const float v = acc[mi][ni][r] - __bfloat162float(sub[row * PDIM + col]);
          outB[row * PDIM + col] = __float2bfloat16(v);
        }
      }
    }
  }
}

__global__ void finalize(float* __restrict__ out, const float* __restrict__ acc) {
  if (threadIdx.x == 0) out[0] = sqrtf(*acc);
}

extern "C" void kernel_launch(void* const* d_in, const int* in_sizes, int n_in,
                              void* d_out, int out_size, void* d_ws, size_t ws_size,
                              hipStream_t stream) {
  const float* X  = (const float*)d_in[0];
  const float* Y  = (const float*)d_in[1];
  const float* Wb = (const float*)d_in[2];
  float* out = (float*)d_out;  // [0]=loss, [1..]=W_matrix (fp32)

  __hip_bfloat16* Xb  = (__hip_bfloat16*)d_ws;
  __hip_bfloat16* XbT = Xb + PPN;
  __hip_bfloat16* Yb  = XbT + PPN;
  __hip_bfloat16* YbT = Yb + PPN;
  __hip_bfloat16* Wbb = YbT + PPN;
  __hip_bfloat16* Wmb = Wbb + PPN;
  __hip_bfloat16* PTb = Xb;  // aliases Xb (dead after GEMM1)
  float* scale   = (float*)(Wmb + PPN);
  float* sAcc    = scale + PDIM;
  float* lossAcc = sAcc + 1;

  hipMemsetAsync(sAcc, 0, 2 * sizeof(float), stream);

  sumsq<<<1024, 256, 0, stream>>>((const float4*)X, sAcc);

  dim3 cgrid(PDIM / 64, PDIM / 64);
  cast_nt<<<cgrid, 256, 0, stream>>>(X, Xb, XbT);
  cast_nt<<<cgrid, 256, 0, stream>>>(Y, Yb, YbT);
  cast_wb_rows<<<PDIM, 256, 0, stream>>>(Wb, Wbb, sAcc, scale);

  dim3 ggrid(PDIM / 128, PDIM / 128);
  gemm_nt<0><<<ggrid, 256, 0, stream>>>(Yb, Xb, scale, out + 1, Wmb, nullptr, nullptr);
  gemm_nt<1><<<ggrid, 256, 0, stream>>>(XbT, Wmb, nullptr, nullptr, PTb, YbT, nullptr);
  gemm_nt<2><<<ggrid, 256, 0, stream>>>(PTb, Wbb, nullptr, nullptr, nullptr, nullptr, lossAcc);

  finalize<<<1, 1, 0, stream>>>(out, lossAcc);
}

// Round 5
// 602.908 us; speedup vs baseline: 1.5204x; 1.3522x over previous
//
#include <hip/hip_runtime.h>
#include <hip/hip_bf16.h>

#define PDIM 4096
#define PPN ((size_t)PDIM * (size_t)PDIM)

typedef __attribute__((ext_vector_type(8))) short bf16x8;
typedef __attribute__((ext_vector_type(4))) float floatx4;
typedef __attribute__((ext_vector_type(8))) int int8v;

__device__ __forceinline__ void load_lds16(const void* g, void* l) {
  __builtin_amdgcn_global_load_lds(
      (const __attribute__((address_space(1))) void*)g,
      (__attribute__((address_space(3))) void*)l, 16, 0, 0);
}

__device__ __forceinline__ unsigned short bf16bits(float f) {
  __hip_bfloat16 h = __float2bfloat16(f);
  return *(unsigned short*)&h;
}

__device__ __forceinline__ unsigned char fp8byte(float v) {
  return (unsigned char)(__builtin_amdgcn_cvt_pk_fp8_f32(v, v, 0, false) & 0xff);
}
__device__ __forceinline__ unsigned int fp8x4(float a, float b, float c, float d) {
  int v = __builtin_amdgcn_cvt_pk_fp8_f32(a, b, 0, false);
  v = __builtin_amdgcn_cvt_pk_fp8_f32(c, d, v, true);
  return (unsigned int)v;
}

// ---- ||X||_F^2: grid-stride, 1 atomic per block ----
__global__ void sumsq(const float4* __restrict__ x, float* __restrict__ acc) {
  float s = 0.f;
  const size_t n4 = PPN / 4;
  for (size_t i = (size_t)blockIdx.x * 256 + threadIdx.x; i < n4;
       i += (size_t)gridDim.x * 256) {
    const float4 v = x[i];
    s += v.x * v.x + v.y * v.y + v.z * v.z + v.w * v.w;
  }
#pragma unroll
  for (int off = 32; off > 0; off >>= 1) s += __shfl_down(s, off);
  __shared__ float ws[4];
  if ((threadIdx.x & 63) == 0) ws[threadIdx.x >> 6] = s;
  __syncthreads();
  if (threadIdx.x == 0) atomicAdd(acc, ws[0] + ws[1] + ws[2] + ws[3]);
}

// ---- X: fp32 -> bf16 (normal) + fp8 e4m3 (transposed) ----
__global__ void cast_x(const float* __restrict__ src,
                       __hip_bfloat16* __restrict__ dstN,
                       unsigned char* __restrict__ dstT8) {
  __shared__ float tile[64][65];
  const int bx = blockIdx.x * 64, by = blockIdx.y * 64;
  const int tx = threadIdx.x & 15, ty = threadIdx.x >> 4;
#pragma unroll
  for (int r = 0; r < 4; ++r) {
    const int row = ty + r * 16;
    const float4 v = *(const float4*)&src[(size_t)(by + row) * PDIM + bx + tx * 4];
    tile[row][tx * 4 + 0] = v.x;
    tile[row][tx * 4 + 1] = v.y;
    tile[row][tx * 4 + 2] = v.z;
    tile[row][tx * 4 + 3] = v.w;
    ushort4 o;
    o.x = bf16bits(v.x); o.y = bf16bits(v.y); o.z = bf16bits(v.z); o.w = bf16bits(v.w);
    *(ushort4*)&dstN[(size_t)(by + row) * PDIM + bx + tx * 4] = o;
  }
  __syncthreads();
#pragma unroll
  for (int r = 0; r < 4; ++r) {
    const int i = ty + r * 16;
    *(unsigned int*)&dstT8[(size_t)(bx + i) * PDIM + by + tx * 4] =
        fp8x4(tile[tx * 4 + 0][i], tile[tx * 4 + 1][i],
              tile[tx * 4 + 2][i], tile[tx * 4 + 3][i]);
  }
}

// ---- Y: fp32 -> bf16 normal + bf16 transposed ----
__global__ void cast_y(const float* __restrict__ src,
                       __hip_bfloat16* __restrict__ dstN,
                       __hip_bfloat16* __restrict__ dstT) {
  __shared__ float tile[64][65];
  const int bx = blockIdx.x * 64, by = blockIdx.y * 64;
  const int tx = threadIdx.x & 15, ty = threadIdx.x >> 4;
#pragma unroll
  for (int r = 0; r < 4; ++r) {
    const int row = ty + r * 16;
    const float4 v = *(const float4*)&src[(size_t)(by + row) * PDIM + bx + tx * 4];
    tile[row][tx * 4 + 0] = v.x;
    tile[row][tx * 4 + 1] = v.y;
    tile[row][tx * 4 + 2] = v.z;
    tile[row][tx * 4 + 3] = v.w;
    ushort4 o;
    o.x = bf16bits(v.x); o.y = bf16bits(v.y); o.z = bf16bits(v.z); o.w = bf16bits(v.w);
    *(ushort4*)&dstN[(size_t)(by + row) * PDIM + bx + tx * 4] = o;
  }
  __syncthreads();
#pragma unroll
  for (int r = 0; r < 4; ++r) {
    const int i = ty + r * 16;
    ushort4 o;
    o.x = bf16bits(tile[tx * 4 + 0][i]);
    o.y = bf16bits(tile[tx * 4 + 1][i]);
    o.z = bf16bits(tile[tx * 4 + 2][i]);
    o.w = bf16bits(tile[tx * 4 + 3][i]);
    *(ushort4*)&dstT[(size_t)(bx + i) * PDIM + by + tx * 4] = o;
  }
}

// ---- W_beta: fp8 cast + row-sum + scale[i] = W^2/(s*W^2+1) ----
__global__ void cast_wb_rows(const float* __restrict__ Wb,
                             unsigned char* __restrict__ Wb8,
                             const float* __restrict__ sAcc,
                             float* __restrict__ scale) {
  const size_t row = blockIdx.x;
  const float4* src = (const float4*)(Wb + row * PDIM);
  unsigned int* dst = (unsigned int*)(Wb8 + row * PDIM);
  float sum = 0.f;
#pragma unroll
  for (int it = 0; it < 4; ++it) {
    const int j = threadIdx.x + it * 256;
    const float4 v = src[j];
    sum += (v.x + v.y) + (v.z + v.w);
    dst[j] = fp8x4(v.x, v.y, v.z, v.w);
  }
#pragma unroll
  for (int off = 32; off > 0; off >>= 1) sum += __shfl_down(sum, off);
  __shared__ float ws[4];
  if ((threadIdx.x & 63) == 0) ws[threadIdx.x >> 6] = sum;
  __syncthreads();
  if (threadIdx.x == 0) {
    const float W = ws[0] + ws[1] + ws[2] + ws[3];
    const float w2 = W * W;
    scale[row] = w2 / ((*sAcc) * w2 + 1.0f);
  }
}

// ---- bf16 NT GEMM (GEMM1 only): Wm = scale[i] * Y.X^T ----
// outF fp32 (d_out), Wm8 fp8 scaled by 2^17. XOR-swizzled LDS (0 conflicts).
__global__ __launch_bounds__(256)
void gemm_bf16_wm(const __hip_bfloat16* __restrict__ A,
                  const __hip_bfloat16* __restrict__ B,
                  const float* __restrict__ scale,
                  float* __restrict__ outF,
                  unsigned char* __restrict__ Wm8) {
  __shared__ __align__(16) __hip_bfloat16 As[128 * 32];
  __shared__ __align__(16) __hip_bfloat16 Bs[128 * 32];

  const int tid = threadIdx.x;
  const int lane = tid & 63;
  const int wave = tid >> 6;
  const int wm = wave >> 1, wn = wave & 1;

  const size_t rowA0 = (size_t)blockIdx.y * 128;
  const size_t rowB0 = (size_t)blockIdx.x * 128;

  const int c0 = tid, c1 = tid + 256;
  const int r0 = c0 >> 2, r1 = c1 >> 2;
  const int sc0 = (c0 & 3) ^ ((r0 >> 1) & 3);
  const int sc1 = (c1 & 3) ^ ((r1 >> 1) & 3);
  const __hip_bfloat16* gA0 = A + (rowA0 + (size_t)r0) * PDIM + sc0 * 8;
  const __hip_bfloat16* gA1 = A + (rowA0 + (size_t)r1) * PDIM + sc1 * 8;
  const __hip_bfloat16* gB0 = B + (rowB0 + (size_t)r0) * PDIM + sc0 * 8;
  const __hip_bfloat16* gB1 = B + (rowB0 + (size_t)r1) * PDIM + sc1 * 8;

  char* ldsA0 = (char*)As + wave * 1024;
  char* ldsA1 = (char*)As + 4096 + wave * 1024;
  char* ldsB0 = (char*)Bs + wave * 1024;
  char* ldsB1 = (char*)Bs + 4096 + wave * 1024;

  floatx4 acc[4][4] = {};

  const int fr = lane & 15;
  const int kq = lane >> 4;
  const int sw = (fr >> 1) & 3;
  const int ko = (kq ^ sw) * 16;

  for (int kt = 0; kt < PDIM; kt += 32) {
    load_lds16(gA0 + kt, ldsA0);
    load_lds16(gA1 + kt, ldsA1);
    load_lds16(gB0 + kt, ldsB0);
    load_lds16(gB1 + kt, ldsB1);
    __syncthreads();

    bf16x8 af[4], bfr[4];
#pragma unroll
    for (int mi = 0; mi < 4; ++mi)
      af[mi] = *(const bf16x8*)((const char*)As + (wm * 64 + mi * 16 + fr) * 64 + ko);
#pragma unroll
    for (int ni = 0; ni < 4; ++ni)
      bfr[ni] = *(const bf16x8*)((const char*)Bs + (wn * 64 + ni * 16 + fr) * 64 + ko);
#pragma unroll
    for (int mi = 0; mi < 4; ++mi)
#pragma unroll
      for (int ni = 0; ni < 4; ++ni)
        acc[mi][ni] = __builtin_amdgcn_mfma_f32_16x16x32_bf16(
            af[mi], bfr[ni], acc[mi][ni], 0, 0, 0);
    __syncthreads();
  }

  const size_t row0 = rowA0 + wm * 64;
  const size_t col0 = rowB0 + wn * 64;
  const int lr = (lane >> 4) << 2;
  const int lc = lane & 15;

#pragma unroll
  for (int mi = 0; mi < 4; ++mi) {
#pragma unroll
    for (int r = 0; r < 4; ++r) {
      const size_t row = row0 + mi * 16 + lr + r;
      const float sc = scale[row];
#pragma unroll
      for (int ni = 0; ni < 4; ++ni) {
        const size_t col = col0 + ni * 16 + lc;
        const float v = sc * acc[mi][ni][r];
        outF[row * PDIM + col] = v;
        Wm8[row * PDIM + col] = fp8byte(v * 131072.f);  // 2^17 pre-scale
      }
    }
  }
}

// ---- fp8 NT GEMM, 128x128 tile, BK=128, mfma_scale 16x16x128 (unit scales) ----
// LDS slot (r, s) holds global 16B chunk (r, s ^ (r&7)) -> uniform bank load.
// MODE 1: outP = fp8(acc*2^-17 - sub)   (P^T; B operand was pre-scaled 2^17)
// MODE 2: lossAcc += sum(acc^2)
template <int MODE>
__global__ __launch_bounds__(256)
void gemm_fp8(const unsigned char* __restrict__ A,
              const unsigned char* __restrict__ B,
              const __hip_bfloat16* __restrict__ sub,
              unsigned char* __restrict__ outP,
              float* __restrict__ lossAcc) {
  __shared__ __align__(16) unsigned char As[128 * 128];
  __shared__ __align__(16) unsigned char Bs[128 * 128];

  const int tid = threadIdx.x;
  const int lane = tid & 63;
  const int wave = tid >> 6;
  const int wm = wave >> 1, wn = wave & 1;

  const size_t rowA0 = (size_t)blockIdx.y * 128;
  const size_t rowB0 = (size_t)blockIdx.x * 128;

  const unsigned char* gA[4];
  const unsigned char* gB[4];
  int ldsOff[4];
#pragma unroll
  for (int m = 0; m < 4; ++m) {
    const int ci = tid + m * 256;
    const int r = ci >> 3, s = ci & 7;
    const int cg = s ^ (r & 7);
    gA[m] = A + (rowA0 + (size_t)r) * PDIM + cg * 16;
    gB[m] = B + (rowB0 + (size_t)r) * PDIM + cg * 16;
    ldsOff[m] = m * 4096 + wave * 1024;
  }

  floatx4 acc[4][4] = {};

  const int fr = lane & 15;
  const int e = fr & 7;
  const int q2 = (lane >> 4) << 1;
  const int offLo = (q2 ^ e) << 4;
  const int offHi = ((q2 + 1) ^ e) << 4;
  const int abase = (wm * 64 + fr) * 128;
  const int bbase = (wn * 64 + fr) * 128;

  for (int kt = 0; kt < PDIM; kt += 128) {
#pragma unroll
    for (int m = 0; m < 4; ++m) load_lds16(gA[m] + kt, (char*)As + ldsOff[m]);
#pragma unroll
    for (int m = 0; m < 4; ++m) load_lds16(gB[m] + kt, (char*)Bs + ldsOff[m]);
    __syncthreads();

    union { int8v v; int4 h[2]; } af[4], bg[4];
#pragma unroll
    for (int mi = 0; mi < 4; ++mi) {
      af[mi].h[0] = *(const int4*)(As + abase + mi * 2048 + offLo);
      af[mi].h[1] = *(const int4*)(As + abase + mi * 2048 + offHi);
    }
#pragma unroll
    for (int ni = 0; ni < 4; ++ni) {
      bg[ni].h[0] = *(const int4*)(Bs + bbase + ni * 2048 + offLo);
      bg[ni].h[1] = *(const int4*)(Bs + bbase + ni * 2048 + offHi);
    }
#pragma unroll
    for (int mi = 0; mi < 4; ++mi)
#pragma unroll
      for (int ni = 0; ni < 4; ++ni)
        acc[mi][ni] = __builtin_amdgcn_mfma_scale_f32_16x16x128_f8f6f4(
            af[mi].v, bg[ni].v, acc[mi][ni],
            0 /*fp8*/, 0 /*fp8*/, 0, 0x7F7F7F7F, 0, 0x7F7F7F7F);
    __syncthreads();
  }

  const size_t row0 = rowA0 + wm * 64;
  const size_t col0 = rowB0 + wn * 64;
  const int lr = (lane >> 4) << 2;
  const int lc = lane & 15;

  if constexpr (MODE == 2) {
    float tot = 0.f;
#pragma unroll
    for (int mi = 0; mi < 4; ++mi)
#pragma unroll
      for (int ni = 0; ni < 4; ++ni)
#pragma unroll
        for (int r = 0; r < 4; ++r) tot += acc[mi][ni][r] * acc[mi][ni][r];
#pragma unroll
    for (int off = 32; off > 0; off >>= 1) tot += __shfl_down(tot, off);
    __shared__ float ws[4];
    if (lane == 0) ws[wave] = tot;
    __syncthreads();
    if (tid == 0) atomicAdd(lossAcc, ws[0] + ws[1] + ws[2] + ws[3]);
  } else {
    constexpr float INV = 1.f / 131072.f;
#pragma unroll
    for (int mi = 0; mi < 4; ++mi) {
#pragma unroll
      for (int r = 0; r < 4; ++r) {
        const size_t row = row0 + mi * 16 + lr + r;
#pragma unroll
        for (int ni = 0; ni < 4; ++ni) {
          const size_t col = col0 + ni * 16 + lc;
          const float v = acc[mi][ni][r] * INV - __bfloat162float(sub[row * PDIM + col]);
          outP[row * PDIM + col] = fp8byte(v);
        }
      }
    }
  }
}

__global__ void finalize(float* __restrict__ out, const float* __restrict__ acc) {
  if (threadIdx.x == 0) out[0] = sqrtf(*acc);
}

extern "C" void kernel_launch(void* const* d_in, const int* in_sizes, int n_in,
                              void* d_out, int out_size, void* d_ws, size_t ws_size,
                              hipStream_t stream) {
  const float* X  = (const float*)d_in[0];
  const float* Y  = (const float*)d_in[1];
  const float* Wb = (const float*)d_in[2];
  float* out = (float*)d_out;  // [0]=loss, [1..]=W_matrix (fp32)

  // workspace: 3x bf16 (32MB) + 4x fp8 (16MB) = 160MB + small
  __hip_bfloat16* Xb   = (__hip_bfloat16*)d_ws;           // X bf16   (GEMM1 B)
  __hip_bfloat16* Yb   = Xb + PPN;                        // Y bf16   (GEMM1 A)
  __hip_bfloat16* YbT  = Yb + PPN;                        // Y^T bf16 (GEMM2 epi)
  unsigned char*  XT8  = (unsigned char*)(YbT + PPN);     // X^T fp8  (GEMM2 A)
  unsigned char*  Wm8  = XT8 + PPN;                       // Wm*2^17 fp8 (GEMM2 B)
  unsigned char*  Wb8  = Wm8 + PPN;                       // W_beta fp8 (GEMM3 B)
  unsigned char*  PT8  = Wb8 + PPN;                       // P^T fp8  (GEMM3 A)
  float* scale   = (float*)(PT8 + PPN);                   // [4096]
  float* sAcc    = scale + PDIM;
  float* lossAcc = sAcc + 1;

  hipMemsetAsync(sAcc, 0, 2 * sizeof(float), stream);

  sumsq<<<1024, 256, 0, stream>>>((const float4*)X, sAcc);

  dim3 cgrid(PDIM / 64, PDIM / 64);
  cast_x<<<cgrid, 256, 0, stream>>>(X, Xb, XT8);
  cast_y<<<cgrid, 256, 0, stream>>>(Y, Yb, YbT);
  cast_wb_rows<<<PDIM, 256, 0, stream>>>(Wb, Wb8, sAcc, scale);

  dim3 ggrid(PDIM / 128, PDIM / 128);
  // GEMM1 (bf16): Wm = scale[i] * Y.X^T -> out+1 (fp32), Wm8 (fp8 * 2^17)
  gemm_bf16_wm<<<ggrid, 256, 0, stream>>>(Yb, Xb, scale, out + 1, Wm8);
  // GEMM2 (fp8): PT[b,a] = (XT.Wm8^T)*2^-17 - YT -> PT8
  gemm_fp8<1><<<ggrid, 256, 0, stream>>>(XT8, Wm8, YbT, PT8, nullptr);
  // GEMM3 (fp8): lossAcc += ||Wb.P||_F^2
  gemm_fp8<2><<<ggrid, 256, 0, stream>>>(PT8, Wb8, nullptr, nullptr, lossAcc);

  finalize<<<1, 1, 0, stream>>>(out, lossAcc);
}